// Round 2
// baseline (712.049 us; speedup 1.0000x reference)
//
#include <hip/hip_runtime.h>
#include <hip/hip_bf16.h>

#define BB 2048
#define LL 1024
#define KK 128
#define DD 64
#define HH 4

// ---------------------------------------------------------------------------
// Kernel 1: prep.  q[h]=t@WQ[h]+bQ[h]; wkq[h][d]=(sum_e WK[h][d][e] q[h][e])/8;
// sb[h]=(q[h].bK[h])/8.  Grid 128 x 256 thr; 16 batches/block in 2 groups of 8
// (weights streamed from L1/L2, amortized over 8 batches in registers).
// ---------------------------------------------------------------------------
__global__ __launch_bounds__(256) void prep_kernel(
    const float* __restrict__ tgt, const float* __restrict__ WQ,
    const float* __restrict__ bQ, const float* __restrict__ WK,
    const float* __restrict__ bK, float* __restrict__ wkq_out,
    float* __restrict__ sb_out)
{
    __shared__ float sT[8][64];
    __shared__ float sQ[8][256];
    const int t = threadIdx.x;
    const int h = t >> 6, e = t & 63;
    const float myBQ = bQ[t];
    const float myBK = bK[t];
    for (int g = 0; g < 2; g++) {
        const int b0 = (blockIdx.x * 2 + g) * 8;
        for (int i = t; i < 512; i += 256)
            sT[i >> 6][i & 63] = tgt[(size_t)(b0 + (i >> 6)) * 64 + (i & 63)];
        __syncthreads();
        // q[j][h][e]: wave reads WQ coalesced (256B/iter), reused 8x
        float acc[8];
        #pragma unroll
        for (int j = 0; j < 8; j++) acc[j] = myBQ;
        for (int d = 0; d < 64; d++) {
            float w = WQ[((h << 6) + d) * 64 + e];
            #pragma unroll
            for (int j = 0; j < 8; j++) acc[j] += sT[j][d] * w;
        }
        #pragma unroll
        for (int j = 0; j < 8; j++) sQ[j][t] = acc[j];
        __syncthreads();
        // sb[j][h] = (q . bK)/8 ; wave w == head h
        #pragma unroll
        for (int j = 0; j < 8; j++) {
            float p = acc[j] * myBK;
            #pragma unroll
            for (int o = 32; o > 0; o >>= 1) p += __shfl_xor(p, o);
            if (e == 0) sb_out[(b0 + j) * 4 + h] = p * 0.125f;
        }
        // wkq[j][t]: thread t streams its own WK row (float4), sQ broadcast
        float acc2[8];
        #pragma unroll
        for (int j = 0; j < 8; j++) acc2[j] = 0.f;
        const float* wrow = WK + (size_t)t * 64;
        for (int i = 0; i < 64; i += 4) {
            float4 w4 = *(const float4*)(wrow + i);
            #pragma unroll
            for (int j = 0; j < 8; j++) {
                acc2[j] += w4.x * sQ[j][(h << 6) + i]
                         + w4.y * sQ[j][(h << 6) + i + 1]
                         + w4.z * sQ[j][(h << 6) + i + 2]
                         + w4.w * sQ[j][(h << 6) + i + 3];
            }
        }
        #pragma unroll
        for (int j = 0; j < 8; j++)
            wkq_out[(size_t)(b0 + j) * 256 + t] = acc2[j] * 0.125f;
        __syncthreads();
    }
}

// ---------------------------------------------------------------------------
// Kernel 2: HBM-heavy gather+attention. One block per batch. topk rows into
// LDS (stride 65 -> 2-way max, free), scores = topk.wkq + sb, wave-per-head
// softmax, ctx[h] = attn[h]@topk.
// ---------------------------------------------------------------------------
__global__ __launch_bounds__(256) void attn_kernel(
    const int* __restrict__ idx, const float* __restrict__ seq,
    const float* __restrict__ wkq_in, const float* __restrict__ sb_in,
    float* __restrict__ ctx_out)
{
    __shared__ float sTop[KK * 65];
    __shared__ float sWkq[256];
    __shared__ float sSb[HH];
    __shared__ float sSc[HH * KK];
    __shared__ float sAt[HH * KK];
    __shared__ int sIdx[KK];
    const int t = threadIdx.x;
    const int b = blockIdx.x;
    if (t < KK) sIdx[t] = idx[b * KK + t];
    sWkq[t] = wkq_in[(size_t)b * 256 + t];
    if (t < HH) sSb[t] = sb_in[b * HH + t];
    __syncthreads();
    // gather: 128 rows x 64 fp32 = 128 x 256B; float4/thread, 4 rows per wave
    for (int i = t; i < 2048; i += 256) {
        int row = i >> 4, c0 = (i & 15) * 4;
        float4 v = *(const float4*)(seq + ((size_t)b * LL + sIdx[row]) * DD + c0);
        float* dst = &sTop[row * 65 + c0];
        dst[0] = v.x; dst[1] = v.y; dst[2] = v.z; dst[3] = v.w;
    }
    __syncthreads();
    // scores: 512 outputs, 2/thread; h wave-uniform each pass
    #pragma unroll
    for (int s = 0; s < 2; s++) {
        int id = (s << 8) + t;
        int h = id >> 7, k = id & 127;
        float acc = 0.f;
        #pragma unroll
        for (int d = 0; d < DD; d++)
            acc += sTop[k * 65 + d] * sWkq[(h << 6) + d];
        sSc[(h << 7) + k] = acc + sSb[h];
    }
    __syncthreads();
    // softmax: wave w handles head w (128 scores = 2/lane)
    const int w = t >> 6, lane = t & 63;
    float x0 = sSc[(w << 7) + lane], x1 = sSc[(w << 7) + 64 + lane];
    float m = fmaxf(x0, x1);
    #pragma unroll
    for (int o = 32; o > 0; o >>= 1) m = fmaxf(m, __shfl_xor(m, o));
    float e0 = __expf(x0 - m), e1 = __expf(x1 - m);
    float s = e0 + e1;
    #pragma unroll
    for (int o = 32; o > 0; o >>= 1) s += __shfl_xor(s, o);
    float inv = 1.f / s;
    sAt[(w << 7) + lane] = e0 * inv;
    sAt[(w << 7) + 64 + lane] = e1 * inv;
    __syncthreads();
    // ctx[h=w][d=lane] = sum_k attn[k] * topk[k][d]
    float acc = 0.f;
    #pragma unroll 8
    for (int k = 0; k < KK; k++)
        acc += sAt[(w << 7) + k] * sTop[k * 65 + lane];
    ctx_out[(size_t)b * 256 + t] = acc;
}

// ---------------------------------------------------------------------------
// Kernel 3: heads = ctx@WV + bV; mhta = heads_flat@WO + bO; MLP -> logit.
// Grid 128 x 256 thr; 16 batches/block in 2 groups of 8.
// ---------------------------------------------------------------------------
__global__ __launch_bounds__(256) void out_kernel(
    const float* __restrict__ ctx_in, const float* __restrict__ tgt,
    const float* __restrict__ WV, const float* __restrict__ bV,
    const float* __restrict__ WO, const float* __restrict__ bO,
    const float* __restrict__ W1, const float* __restrict__ b1,
    const float* __restrict__ W2, const float* __restrict__ b2,
    float* __restrict__ outp)
{
    __shared__ float sCtx[8][256];
    __shared__ float sH[8][256];
    __shared__ float sP[8][256];
    __shared__ float sX[8][128];
    const int t = threadIdx.x;
    const int h = t >> 6, e = t & 63;
    const float myBV = bV[t];
    for (int g = 0; g < 2; g++) {
        const int b0 = (blockIdx.x * 2 + g) * 8;
        #pragma unroll
        for (int j = 0; j < 8; j++)
            sCtx[j][t] = ctx_in[(size_t)(b0 + j) * 256 + t];
        for (int i = t; i < 512; i += 256)
            sX[i >> 6][64 + (i & 63)] = tgt[(size_t)(b0 + (i >> 6)) * 64 + (i & 63)];
        __syncthreads();
        // heads[j][h][e] = bV + sum_d ctx[j][h][d] * WV[h][d][e]
        float acc[8];
        #pragma unroll
        for (int j = 0; j < 8; j++) acc[j] = myBV;
        for (int d = 0; d < 64; d++) {
            float w = WV[((h << 6) + d) * 64 + e];
            #pragma unroll
            for (int j = 0; j < 8; j++) acc[j] += sCtx[j][(h << 6) + d] * w;
        }
        #pragma unroll
        for (int j = 0; j < 8; j++) sH[j][t] = acc[j];
        __syncthreads();
        // mhta partials: wave h covers rows he in [h*64, h*64+64)
        float pa[8];
        #pragma unroll
        for (int j = 0; j < 8; j++) pa[j] = 0.f;
        for (int i = 0; i < 64; i++) {
            float w = WO[((h << 6) + i) * 64 + e];
            #pragma unroll
            for (int j = 0; j < 8; j++) pa[j] += sH[j][(h << 6) + i] * w;
        }
        #pragma unroll
        for (int j = 0; j < 8; j++) sP[j][t] = pa[j];
        __syncthreads();
        // mhta[j][e'] = sum of 4 head-partials + bO : 512 outputs, 2/thread
        #pragma unroll
        for (int s = 0; s < 2; s++) {
            int id = (s << 8) + t;
            int j = id >> 6, ee = id & 63;
            sX[j][ee] = sP[j][ee] + sP[j][64 + ee] + sP[j][128 + ee]
                      + sP[j][192 + ee] + bO[ee];
        }
        __syncthreads();
        // MLP: wave handles one batch j per pass (j wave-uniform)
        #pragma unroll
        for (int s = 0; s < 2; s++) {
            int j = (s << 2) + (t >> 6);
            int n = t & 63;
            float a1 = b1[n];
            #pragma unroll 4
            for (int i = 0; i < 128; i++)
                a1 += sX[j][i] * W1[i * 64 + n];
            a1 = fmaxf(a1, 0.f);
            float p = a1 * W2[n];
            #pragma unroll
            for (int o = 32; o > 0; o >>= 1) p += __shfl_xor(p, o);
            if (n == 0) outp[b0 + j] = p + b2[0];
        }
        __syncthreads();
    }
}

extern "C" void kernel_launch(void* const* d_in, const int* in_sizes, int n_in,
                              void* d_out, int out_size, void* d_ws, size_t ws_size,
                              hipStream_t stream)
{
    const int*   idx = (const int*)d_in[0];
    const float* seq = (const float*)d_in[1];
    const float* tgt = (const float*)d_in[2];
    const float* WQ  = (const float*)d_in[3];
    const float* bQ  = (const float*)d_in[4];
    const float* WK  = (const float*)d_in[5];
    const float* bK  = (const float*)d_in[6];
    const float* WV  = (const float*)d_in[7];
    const float* bV  = (const float*)d_in[8];
    const float* WO  = (const float*)d_in[9];
    const float* bO  = (const float*)d_in[10];
    const float* W1  = (const float*)d_in[11];
    const float* b1  = (const float*)d_in[12];
    const float* W2  = (const float*)d_in[13];
    const float* b2  = (const float*)d_in[14];

    float* wkq = (float*)d_ws;                        // [B][256]
    float* sb  = wkq + (size_t)BB * 256;              // [B][4]
    float* ctx = sb + (size_t)BB * 4;                 // [B][256]
    float* outp = (float*)d_out;                      // [B]

    prep_kernel<<<dim3(BB / 16), dim3(256), 0, stream>>>(tgt, WQ, bQ, WK, bK, wkq, sb);
    attn_kernel<<<dim3(BB), dim3(256), 0, stream>>>(idx, seq, wkq, sb, ctx);
    out_kernel<<<dim3(BB / 16), dim3(256), 0, stream>>>(ctx, tgt, WV, bV, WO, bO,
                                                        W1, b1, W2, b2, outp);
}